// Round 4
// baseline (272.838 us; speedup 1.0000x reference)
//
#include <hip/hip_runtime.h>
#include <stdint.h>

typedef __bf16 bf16;
typedef __bf16 bf16x8 __attribute__((ext_vector_type(8)));
typedef float  f32x4  __attribute__((ext_vector_type(4)));
typedef uint32_t u32;
typedef uint64_t u64;

#define SCALE_L2E 0.18033688011112042f   // (1/8) * log2(e)

__device__ __forceinline__ void gld_lds16(const void* gsrc, void* ldst) {
  __builtin_amdgcn_global_load_lds(
      (const __attribute__((address_space(1))) void*)gsrc,
      (__attribute__((address_space(3))) void*)ldst, 16, 0, 0);
}

// ---------------- stage 1: conversions / packing ----------------

__global__ void cvt3(const float* __restrict__ q, const float* __restrict__ k,
                     const float* __restrict__ v, bf16* __restrict__ out) {
  const float* in = (blockIdx.z == 0) ? q : (blockIdx.z == 1) ? k : v;
  bf16* o = out + (size_t)blockIdx.z * 8388608;
  int stride = gridDim.x * blockDim.x;
  for (int i = blockIdx.x * blockDim.x + threadIdx.x; i < 1048576; i += stride) {
    const float4* p = (const float4*)(in + (size_t)i * 8);
    float4 a = p[0], b = p[1];
    bf16x8 vv;
    vv[0]=(bf16)a.x; vv[1]=(bf16)a.y; vv[2]=(bf16)a.z; vv[3]=(bf16)a.w;
    vv[4]=(bf16)b.x; vv[5]=(bf16)b.y; vv[6]=(bf16)b.z; vv[7]=(bf16)b.w;
    *(bf16x8*)(o + (size_t)i * 8) = vv;
  }
}

__global__ void pack_w(const float* __restrict__ Wq, const float* __restrict__ Wk,
                       const float* __restrict__ Wv, const float* __restrict__ Wo,
                       bf16* __restrict__ Wt) {
  int s = blockIdx.z;
  int tid = blockIdx.x * blockDim.x + threadIdx.x;
  int n = tid >> 7, kb = tid & 127;
  const float* W = (s == 0) ? Wq : (s == 1) ? Wk : (s == 2) ? Wv : Wo;
  bf16x8 v;
  if (s < 3) {
#pragma unroll
    for (int j = 0; j < 8; ++j)
      v[j] = (bf16)W[((n >> 6) << 16) + (kb * 8 + j) * 64 + (n & 63)];
  } else {
    const float4* p = (const float4*)&W[n * 1024 + kb * 8];
    float4 a = p[0], b = p[1];
    v[0]=(bf16)a.x; v[1]=(bf16)a.y; v[2]=(bf16)a.z; v[3]=(bf16)a.w;
    v[4]=(bf16)b.x; v[5]=(bf16)b.y; v[6]=(bf16)b.z; v[7]=(bf16)b.w;
  }
  *(bf16x8*)&Wt[(size_t)s * 1048576 + (size_t)n * 1024 + kb * 8] = v;
}

__global__ void pack_mask(const int* __restrict__ mask, u32* __restrict__ mbits, int total) {
  int stride = gridDim.x * blockDim.x;
  for (int idx = blockIdx.x * blockDim.x + threadIdx.x; idx < total; idx += stride) {
    int v = mask[idx];
    u64 bal = __ballot(v != 0);
    if ((threadIdx.x & 63) == 0)
      *(u64*)&mbits[idx >> 5] = bal;
  }
}

// ---------------- stage 2: bf16 GEMM, 2-phase double-buffered ----------------
template<int EPI>
__global__ __launch_bounds__(256, 2)
void gemm_bt(const bf16* __restrict__ A, const bf16* __restrict__ Bt,
             void* __restrict__ Cout, void* __restrict__ Cout2,
             const float* __restrict__ bias,
             size_t a_bstride, size_t b_bstride, float cscale) {
  const int gx = gridDim.x;
  int lin = blockIdx.y * gx + blockIdx.x;
  int nwg = gx * gridDim.y;
  int swz = (lin & 7) * (nwg >> 3) + (lin >> 3);
  int bx = swz % gx, by = swz / gx;
  const int bz = blockIdx.z;
  A  += a_bstride * bz;
  Bt += b_bstride * bz;
  const int row0 = by * 128, col0 = bx * 128;
  bool isK = false;
  if (EPI == 0 && row0 >= 8192) { isK = true; Bt += 1048576; }

  __shared__ bf16 sA[2][4096];
  __shared__ bf16 sB[2][4096];

  const int lane = threadIdx.x & 63, w = threadIdx.x >> 6;
  const int c = lane & 15, g = lane >> 4;
  const int wr = w >> 1, wc = w & 1;

  const int u0 = w * 128 + lane;
  const int rs0 = u0 >> 2, ps0 = u0 & 3;
  const int rs1 = (u0 + 64) >> 2, ps1 = (u0 + 64) & 3;
  const bf16* Ap = A + (size_t)row0 * 1024;
  const bf16* Bp = Bt + (size_t)col0 * 1024;
  const bf16* As0 = Ap + (size_t)rs0 * 1024 + ps0 * 8;
  const bf16* As1 = Ap + (size_t)rs1 * 1024 + ps1 * 8;
  const bf16* Bs0 = Bp + (size_t)rs0 * 1024 + ps0 * 8;
  const bf16* Bs1 = Bp + (size_t)rs1 * 1024 + ps1 * 8;

  f32x4 acc[4][4] = {};

  gld_lds16(As0, (char*)&sA[0][0] + (w * 2) * 1024);
  gld_lds16(As1, (char*)&sA[0][0] + (w * 2 + 1) * 1024);
  gld_lds16(Bs0, (char*)&sB[0][0] + (w * 2) * 1024);
  gld_lds16(Bs1, (char*)&sB[0][0] + (w * 2 + 1) * 1024);

  for (int k0 = 0; k0 < 1024; k0 += 32) {
    __syncthreads();
    int cb = (k0 >> 5) & 1, nb = cb ^ 1;
    if (k0 < 992) {
      gld_lds16(As0 + k0 + 32, (char*)&sA[nb][0] + (w * 2) * 1024);
      gld_lds16(As1 + k0 + 32, (char*)&sA[nb][0] + (w * 2 + 1) * 1024);
      gld_lds16(Bs0 + k0 + 32, (char*)&sB[nb][0] + (w * 2) * 1024);
      gld_lds16(Bs1 + k0 + 32, (char*)&sB[nb][0] + (w * 2 + 1) * 1024);
    }

    bf16x8 af[4], bfr[4];
#pragma unroll
    for (int m = 0; m < 4; ++m)
      af[m] = *(const bf16x8*)&sA[cb][(wr * 64 + m * 16 + c) * 32 + g * 8];
#pragma unroll
    for (int n = 0; n < 4; ++n)
      bfr[n] = *(const bf16x8*)&sB[cb][(wc * 64 + n * 16 + c) * 32 + g * 8];
#pragma unroll
    for (int m = 0; m < 4; ++m)
#pragma unroll
      for (int n = 0; n < 4; ++n)
        acc[m][n] = __builtin_amdgcn_mfma_f32_16x16x32_bf16(af[m], bfr[n], acc[m][n], 0, 0, 0);
  }

  float csc = (EPI == 0 && isK) ? 1.0f : cscale;
#pragma unroll
  for (int m = 0; m < 4; ++m) {
    int row_base = row0 + wr * 64 + m * 16 + g * 4;
#pragma unroll
    for (int n = 0; n < 4; ++n) {
      int col = col0 + wc * 64 + n * 16 + c;
#pragma unroll
      for (int r = 0; r < 4; ++r) {
        int row = row_base + r;
        float val = acc[m][n][r];
        if (EPI == 0) {
          int rl = row & 8191;
          int b = rl >> 11, l = rl & 2047, h = col >> 6, d = col & 63;
          bf16* dst = isK ? (bf16*)Cout2 : (bf16*)Cout;
          dst[(((size_t)(b * 16 + h) * 2048 + l) << 6) + d] = (bf16)(val * csc);
        } else if (EPI == 1) {
          ((bf16*)Cout)[((size_t)(bz * 1024 + row)) * 2048 + col] = (bf16)val;
        } else {
          ((float*)Cout)[(size_t)row * 1024 + col] = val + bias[col];
        }
      }
    }
  }
}

// ---------------- stage 3: flash attention, T15-staggered ----------------
// iter t: QK(t+1) [MFMA] issued BEFORE softmax(t) [VALU] + PV(t) [MFMA] — the
// SM consumes scores produced a full iteration earlier, so QK latency is free
// and MFMA/VALU streams interleave. Denominator comes from mfma(ones, P).

#define ATTN_ITER(t, PAR, SP, SC)                                              \
  {                                                                            \
    const char* kbC = sKV + ((PAR) << 14);                                     \
    const char* kbN = sKV + (((PAR) ^ 1) << 14);                               \
    if ((t) < 31) {                                                            \
      __builtin_amdgcn_s_setprio(1);                                           \
      _Pragma("unroll")                                                        \
      for (int nk = 0; nk < 4; ++nk) {                                         \
        bf16x8 kfa = *(const bf16x8*)(kbN + ko0 + nk * 2048);                  \
        bf16x8 kfb = *(const bf16x8*)(kbN + ko1 + nk * 2048);                  \
        f32x4 z = {0.f, 0.f, 0.f, 0.f};                                        \
        SC[nk][0] = __builtin_amdgcn_mfma_f32_16x16x32_bf16(kfb, qf[0][1],     \
            __builtin_amdgcn_mfma_f32_16x16x32_bf16(kfa, qf[0][0], z, 0,0,0),  \
            0, 0, 0);                                                          \
        SC[nk][1] = __builtin_amdgcn_mfma_f32_16x16x32_bf16(kfb, qf[1][1],     \
            __builtin_amdgcn_mfma_f32_16x16x32_bf16(kfa, qf[1][0], z, 0,0,0),  \
            0, 0, 0);                                                          \
      }                                                                        \
      __builtin_amdgcn_s_setprio(0);                                           \
    }                                                                          \
    if ((t) < 30) {                                                            \
      kr0 = *(const uint4*)(gK0 + (size_t)((t) + 2) * 4096);                   \
      kr1 = *(const uint4*)(gK1 + (size_t)((t) + 2) * 4096);                   \
      vr0 = *(const uint4*)(gV0 + (size_t)((t) + 2) * 64);                     \
      vr1 = *(const uint4*)(gV1 + (size_t)((t) + 2) * 64);                     \
      mwi0 = Mrow0[(t) + 2];                                                   \
      mwi1 = Mrow1[(t) + 2];                                                   \
    }                                                                          \
    _Pragma("unroll")                                                          \
    for (int nq = 0; nq < 2; ++nq) {                                           \
      u64 ms = (nq ? mwc1 : mwc0) >> (4 * g);                                  \
      u32 ma = (u32)ms, mb2 = (u32)(ms >> 32);                                 \
      _Pragma("unroll")                                                        \
      for (int nk = 0; nk < 4; ++nk) {                                         \
        u32 msel = (nk < 2) ? ma : mb2;                                        \
        const int bs = (nk & 1) * 16;                                          \
        float e0 = __builtin_amdgcn_exp2f(SP[nk][nq][0]);                      \
        float e1 = __builtin_amdgcn_exp2f(SP[nk][nq][1]);                      \
        float e2 = __builtin_amdgcn_exp2f(SP[nk][nq][2]);                      \
        float e3 = __builtin_amdgcn_exp2f(SP[nk][nq][3]);                      \
        e0 = (msel & (1u << (bs + 0))) ? e0 : 0.f;                             \
        e1 = (msel & (1u << (bs + 1))) ? e1 : 0.f;                             \
        e2 = (msel & (1u << (bs + 2))) ? e2 : 0.f;                             \
        e3 = (msel & (1u << (bs + 3))) ? e3 : 0.f;                             \
        union { bf16 h[4]; uint2 d; } pk;                                      \
        pk.h[0] = (bf16)e0; pk.h[1] = (bf16)e1;                                \
        pk.h[2] = (bf16)e2; pk.h[3] = (bf16)e3;                                \
        *(uint2*)(pw[nk] + nq * 2048) = pk.d;                                  \
      }                                                                        \
    }                                                                          \
    __builtin_amdgcn_s_setprio(1);                                             \
    _Pragma("unroll")                                                          \
    for (int kk = 0; kk < 2; ++kk) {                                           \
      const char* pa = kk ? paddr1 : paddr0;                                   \
      const int vo = kk ? vo1 : vo0;                                           \
      bf16x8 pf0 = *(const bf16x8*)(pa);                                       \
      bf16x8 pf1 = *(const bf16x8*)(pa + 2048);                                \
      dacc[0] = __builtin_amdgcn_mfma_f32_16x16x32_bf16(onesv, pf0, dacc[0], 0, 0, 0); \
      dacc[1] = __builtin_amdgcn_mfma_f32_16x16x32_bf16(onesv, pf1, dacc[1], 0, 0, 0); \
      _Pragma("unroll")                                                        \
      for (int md = 0; md < 4; ++md) {                                         \
        bf16x8 vf = *(const bf16x8*)(kbC + vo + md * 2048);                    \
        oacc[md][0] = __builtin_amdgcn_mfma_f32_16x16x32_bf16(vf, pf0, oacc[md][0], 0, 0, 0); \
        oacc[md][1] = __builtin_amdgcn_mfma_f32_16x16x32_bf16(vf, pf1, oacc[md][1], 0, 0, 0); \
      }                                                                        \
    }                                                                          \
    __builtin_amdgcn_s_setprio(0);                                             \
    __syncthreads();                                                           \
    if ((t) < 30) {                                                            \
      char* nb = sKV + ((PAR) << 14);                                          \
      *(uint4*)(nb + dK0o) = kr0; *(uint4*)(nb + dK1o) = kr1;                  \
      *(uint4*)(nb + dV0o) = vr0; *(uint4*)(nb + dV1o) = vr1;                  \
    }                                                                          \
    mwc0 = mwn0; mwc1 = mwn1; mwn0 = mwi0; mwn1 = mwi1;                        \
    __syncthreads();                                                           \
  }

__global__ __launch_bounds__(256, 2)
void attn_fwd(const bf16* __restrict__ Qp, const bf16* __restrict__ Kp,
              const bf16* __restrict__ Vt, const u32* __restrict__ mbits,
              bf16* __restrict__ X) {
  int lin = blockIdx.y * 16 + blockIdx.x;
  int swz = (lin & 7) * 128 + (lin >> 3);
  int qt = swz & 15, bh = swz >> 4;
  int b = bh >> 4, h = bh & 15;
  int q0 = qt * 128;

  const int tid = threadIdx.x;
  const int lane = tid & 63, w = tid >> 6;
  const int c = lane & 15, g = lane >> 4;

  __shared__ char smem[49152];
  char* sKV = smem;                        // 2 slots x {K 8K | V 8K}, XOR swizzled
  char* sPw = smem + 32768 + w * 4096;     // per-wave P: [32 q][64 keys] bf16

  const int c7 = c & 7;
  const int y0 = (g ^ c7) << 4;
  const int y1 = ((4 + g) ^ c7) << 4;
  const int ko0 = c * 128 + y0;
  const int ko1 = c * 128 + y1;
  const int vo0 = 8192 + c * 128 + y0;
  const int vo1 = 8192 + c * 128 + y1;
  const char* paddr0 = sPw + c * 128 + y0;
  const char* paddr1 = sPw + c * 128 + y1;
  char* pw[4];
#pragma unroll
  for (int nk = 0; nk < 4; ++nk)
    pw[nk] = sPw + c * 128 + ((g & 1) * 8) + (((nk * 2 + (g >> 1)) ^ c7) << 4);

  const int r0 = tid >> 3, bb0 = tid & 7;
  const int r1 = (256 + tid) >> 3, bb1 = tid & 7;
  const int dK0o = r0 * 128 + ((bb0 ^ (r0 & 7)) << 4);
  const int dK1o = r1 * 128 + ((bb1 ^ (r1 & 7)) << 4);
  const int dV0o = 8192 + dK0o;
  const int dV1o = 8192 + dK1o;
  const bf16* gK0 = Kp + (size_t)bh * 131072 + r0 * 64 + bb0 * 8;
  const bf16* gK1 = Kp + (size_t)bh * 131072 + r1 * 64 + bb1 * 8;
  const bf16* gV0 = Vt + ((size_t)(b * 1024 + h * 64 + r0)) * 2048 + bb0 * 8;
  const bf16* gV1 = Vt + ((size_t)(b * 1024 + h * 64 + r1)) * 2048 + bb1 * 8;

  const bf16* Qbase = Qp + ((size_t)bh * 2048) * 64;
  bf16x8 qf[2][2];
#pragma unroll
  for (int nq = 0; nq < 2; ++nq) {
    int qg = q0 + w * 32 + nq * 16 + c;
#pragma unroll
    for (int kk = 0; kk < 2; ++kk)
      qf[nq][kk] = *(const bf16x8*)&Qbase[(size_t)qg * 64 + kk * 32 + g * 8];
  }

  bf16x8 onesv;
#pragma unroll
  for (int i = 0; i < 8; ++i) onesv[i] = (bf16)1.0f;

  const u64* Mrow0 = (const u64*)(mbits + ((size_t)b * 2048 + (q0 + w * 32 + c)) * 64);
  const u64* Mrow1 = (const u64*)(mbits + ((size_t)b * 2048 + (q0 + w * 32 + 16 + c)) * 64);

  f32x4 oacc[4][2] = {};
  f32x4 dacc[2] = {};
  f32x4 sa[4][2], sb[4][2];
  uint4 kr0, kr1, vr0, vr1;
  u64 mwc0, mwc1, mwn0, mwn1, mwi0 = 0, mwi1 = 0;

  // prologue: tiles 0,1 -> slots 0,1 ; QK(0) -> sa
  {
    uint4 a0 = *(const uint4*)gK0, a1 = *(const uint4*)gK1;
    uint4 b0 = *(const uint4*)gV0, b1 = *(const uint4*)gV1;
    uint4 c0 = *(const uint4*)(gK0 + 4096), c1 = *(const uint4*)(gK1 + 4096);
    uint4 d0 = *(const uint4*)(gV0 + 64),   d1 = *(const uint4*)(gV1 + 64);
    *(uint4*)(sKV + dK0o) = a0; *(uint4*)(sKV + dK1o) = a1;
    *(uint4*)(sKV + dV0o) = b0; *(uint4*)(sKV + dV1o) = b1;
    *(uint4*)(sKV + 16384 + dK0o) = c0; *(uint4*)(sKV + 16384 + dK1o) = c1;
    *(uint4*)(sKV + 16384 + dV0o) = d0; *(uint4*)(sKV + 16384 + dV1o) = d1;
  }
  mwc0 = Mrow0[0]; mwc1 = Mrow1[0];
  mwn0 = Mrow0[1]; mwn1 = Mrow1[1];
  __syncthreads();

  __builtin_amdgcn_s_setprio(1);
#pragma unroll
  for (int nk = 0; nk < 4; ++nk) {
    bf16x8 kfa = *(const bf16x8*)(sKV + ko0 + nk * 2048);
    bf16x8 kfb = *(const bf16x8*)(sKV + ko1 + nk * 2048);
    f32x4 z = {0.f, 0.f, 0.f, 0.f};
    sa[nk][0] = __builtin_amdgcn_mfma_f32_16x16x32_bf16(kfb, qf[0][1],
        __builtin_amdgcn_mfma_f32_16x16x32_bf16(kfa, qf[0][0], z, 0, 0, 0), 0, 0, 0);
    sa[nk][1] = __builtin_amdgcn_mfma_f32_16x16x32_bf16(kfb, qf[1][1],
        __builtin_amdgcn_mfma_f32_16x16x32_bf16(kfa, qf[1][0], z, 0, 0, 0), 0, 0, 0);
  }
  __builtin_amdgcn_s_setprio(0);

  for (int t2 = 0; t2 < 16; ++t2) {
    int ta = 2 * t2, tb = 2 * t2 + 1;
    ATTN_ITER(ta, 0, sa, sb);
    ATTN_ITER(tb, 1, sb, sa);
  }

  float inv0 = 1.f / dacc[0][0];
  float inv1 = 1.f / dacc[1][0];

  // epilogue: O^T -> LDS transpose -> coalesced bf16 write
  char* Xl = smem;
#pragma unroll
  for (int nq = 0; nq < 2; ++nq) {
    float inv = nq ? inv1 : inv0;
    int ql = w * 32 + nq * 16 + c;
#pragma unroll
    for (int md = 0; md < 4; ++md)
#pragma unroll
      for (int r = 0; r < 4; ++r) {
        int d = md * 16 + g * 4 + r;
        int blk = d >> 3, off = d & 7;
        *(bf16*)(Xl + ql * 128 + ((blk ^ (ql & 7)) << 4) + off * 2) =
            (bf16)(oacc[md][nq][r] * inv);
      }
  }
  __syncthreads();
#pragma unroll
  for (int i = 0; i < 4; ++i) {
    int u = i * 256 + tid;
    int row = u >> 3, blk = u & 7;
    uint4 xv = *(const uint4*)(Xl + row * 128 + ((blk ^ (row & 7)) << 4));
    *(uint4*)&X[(size_t)(b * 2048 + q0 + row) * 1024 + h * 64 + blk * 8] = xv;
  }
}

// ---------------- launch ----------------

extern "C" void kernel_launch(void* const* d_in, const int* in_sizes, int n_in,
                              void* d_out, int out_size, void* d_ws, size_t ws_size,
                              hipStream_t stream) {
  const float* q    = (const float*)d_in[0];
  const float* k    = (const float*)d_in[1];
  const float* v    = (const float*)d_in[2];
  const int*   mask = (const int*)d_in[3];
  const float* Wq   = (const float*)d_in[4];
  const float* Wk   = (const float*)d_in[5];
  const float* Wv   = (const float*)d_in[6];
  const float* Wo   = (const float*)d_in[7];
  const float* Wb   = (const float*)d_in[8];

  char* ws = (char*)d_ws;
  bf16* qb = (bf16*)(ws + 0);
  bf16* kb = (bf16*)(ws + 16777216);
  bf16* vb = (bf16*)(ws + 33554432);
  bf16* Wt = (bf16*)(ws + 50331648);
  bf16* Qp = (bf16*)(ws + 58720256);
  bf16* Kp = (bf16*)(ws + 75497472);
  bf16* Vt = (bf16*)(ws + 92274688);
  bf16* Xb = (bf16*)(ws + 109051904);
  u32*  mb = (u32*) (ws + 125829120);

  cvt3<<<dim3(512, 1, 3), 256, 0, stream>>>(q, k, v, qb);
  pack_w<<<dim3(512, 1, 4), 256, 0, stream>>>(Wq, Wk, Wv, Wo, Wt);
  pack_mask<<<2048, 256, 0, stream>>>(mask, mb, 16777216);

  gemm_bt<0><<<dim3(8, 128, 1), 256, 0, stream>>>(qb, Wt, Qp, Kp, nullptr, 0, 0, SCALE_L2E);
  gemm_bt<1><<<dim3(16, 8, 4), 256, 0, stream>>>(Wt + 2097152, vb, Vt, nullptr, nullptr, 0, 2097152, 1.0f);

  attn_fwd<<<dim3(16, 64, 1), 256, 0, stream>>>(Qp, Kp, Vt, mb, Xb);

  gemm_bt<2><<<dim3(8, 64, 1), 256, 0, stream>>>(Xb, Wt + 3145728, (float*)d_out, nullptr, Wb, 0, 0, 1.0f);
}

// Round 5
// 263.612 us; speedup vs baseline: 1.0350x; 1.0350x over previous
//
#include <hip/hip_runtime.h>
#include <stdint.h>

typedef __bf16 bf16;
typedef __bf16 bf16x8 __attribute__((ext_vector_type(8)));
typedef float  f32x4  __attribute__((ext_vector_type(4)));
typedef uint32_t u32;
typedef uint64_t u64;

#define SCALE_L2E 0.18033688011112042f   // (1/8) * log2(e)

__device__ __forceinline__ void gld_lds16(const void* gsrc, void* ldst) {
  __builtin_amdgcn_global_load_lds(
      (const __attribute__((address_space(1))) void*)gsrc,
      (__attribute__((address_space(3))) void*)ldst, 16, 0, 0);
}

// ---------------- stage 1: conversions / packing ----------------

__global__ void cvt3(const float* __restrict__ q, const float* __restrict__ k,
                     const float* __restrict__ v, bf16* __restrict__ out) {
  const float* in = (blockIdx.z == 0) ? q : (blockIdx.z == 1) ? k : v;
  bf16* o = out + (size_t)blockIdx.z * 8388608;
  int stride = gridDim.x * blockDim.x;
  for (int i = blockIdx.x * blockDim.x + threadIdx.x; i < 1048576; i += stride) {
    const float4* p = (const float4*)(in + (size_t)i * 8);
    float4 a = p[0], b = p[1];
    bf16x8 vv;
    vv[0]=(bf16)a.x; vv[1]=(bf16)a.y; vv[2]=(bf16)a.z; vv[3]=(bf16)a.w;
    vv[4]=(bf16)b.x; vv[5]=(bf16)b.y; vv[6]=(bf16)b.z; vv[7]=(bf16)b.w;
    *(bf16x8*)(o + (size_t)i * 8) = vv;
  }
}

__global__ void pack_w(const float* __restrict__ Wq, const float* __restrict__ Wk,
                       const float* __restrict__ Wv, const float* __restrict__ Wo,
                       bf16* __restrict__ Wt) {
  int s = blockIdx.z;
  int tid = blockIdx.x * blockDim.x + threadIdx.x;
  int n = tid >> 7, kb = tid & 127;
  const float* W = (s == 0) ? Wq : (s == 1) ? Wk : (s == 2) ? Wv : Wo;
  bf16x8 v;
  if (s < 3) {
#pragma unroll
    for (int j = 0; j < 8; ++j)
      v[j] = (bf16)W[((n >> 6) << 16) + (kb * 8 + j) * 64 + (n & 63)];
  } else {
    const float4* p = (const float4*)&W[n * 1024 + kb * 8];
    float4 a = p[0], b = p[1];
    v[0]=(bf16)a.x; v[1]=(bf16)a.y; v[2]=(bf16)a.z; v[3]=(bf16)a.w;
    v[4]=(bf16)b.x; v[5]=(bf16)b.y; v[6]=(bf16)b.z; v[7]=(bf16)b.w;
  }
  *(bf16x8*)&Wt[(size_t)s * 1048576 + (size_t)n * 1024 + kb * 8] = v;
}

__global__ void pack_mask(const int* __restrict__ mask, u32* __restrict__ mbits, int total) {
  int stride = gridDim.x * blockDim.x;
  for (int idx = blockIdx.x * blockDim.x + threadIdx.x; idx < total; idx += stride) {
    int v = mask[idx];
    u64 bal = __ballot(v != 0);
    if ((threadIdx.x & 63) == 0)
      *(u64*)&mbits[idx >> 5] = bal;
  }
}

// ---------------- stage 2: bf16 GEMM, BK=64, XOR-swizzled LDS, dbuf ----------------
// LDS tile [128 rows][64 k] bf16, 128B rows of 8 x 16B blocks; logical block l of
// row r lives at physical block l^(r&7). Staged via global_load_lds with the
// inverse swizzle applied to the per-lane GLOBAL address (LDS dest linear).
// Fragment ds_read_b128: banks ((kk*4+g)^ (c&7))*4 -> 8-block spread, conflict-free.
template<int EPI>
__global__ __launch_bounds__(256, 2)
void gemm_bt(const bf16* __restrict__ A, const bf16* __restrict__ Bt,
             void* __restrict__ Cout, void* __restrict__ Cout2,
             const float* __restrict__ bias,
             size_t a_bstride, size_t b_bstride, float cscale) {
  const int gx = gridDim.x;
  int lin = blockIdx.y * gx + blockIdx.x;
  int nwg = gx * gridDim.y;
  int swz = (lin & 7) * (nwg >> 3) + (lin >> 3);   // nwg % 8 == 0
  int bx = swz % gx, by = swz / gx;
  const int bz = blockIdx.z;
  A  += a_bstride * bz;
  Bt += b_bstride * bz;
  const int row0 = by * 128, col0 = bx * 128;
  bool isK = false;
  if (EPI == 0 && row0 >= 8192) { isK = true; Bt += 1048576; }

  __shared__ bf16 sA[2][8192];   // 16 KB per buf
  __shared__ bf16 sB[2][8192];

  const int lane = threadIdx.x & 63, w = threadIdx.x >> 6;
  const int c = lane & 15, g = lane >> 4;
  const int wr = w >> 1, wc = w & 1;
  const int c7 = c & 7;

  // ---- staging: wave w stages chunks j=w*4+ii (8 rows x 128B each) of A and B.
  // lane: row_in_chunk = lane>>3; source k-block pre-swizzled so linear LDS
  // slot (lane&7) receives logical block (lane&7)^(row&7).
  const int ric = lane >> 3;
  const int pblk = (lane & 7) ^ (ric & 7);
  const bf16* Ap = A + (size_t)row0 * 1024;
  const bf16* Bp = Bt + (size_t)col0 * 1024;
  const bf16* Asrc[4];
  const bf16* Bsrc[4];
#pragma unroll
  for (int ii = 0; ii < 4; ++ii) {
    int r = 8 * (w * 4 + ii) + ric;
    Asrc[ii] = Ap + (size_t)r * 1024 + pblk * 8;
    Bsrc[ii] = Bp + (size_t)r * 1024 + pblk * 8;
  }

  // ---- fragment read offsets (bytes, within a buffer) ----
  const int y0 = (g ^ c7) << 4;          // kk=0 : logical block g
  const int y1 = ((4 + g) ^ c7) << 4;    // kk=1 : logical block 4+g
  const int abase = wr * 8192 + c * 128; // row = wr*64 + m*16 + c  (m via +m*2048)
  const int bbase = wc * 8192 + c * 128;

  f32x4 acc[4][4] = {};

  // prologue: stage k-tile 0 into buf 0
#pragma unroll
  for (int ii = 0; ii < 4; ++ii) {
    gld_lds16(Asrc[ii], (char*)&sA[0][0] + (w * 4 + ii) * 1024);
    gld_lds16(Bsrc[ii], (char*)&sB[0][0] + (w * 4 + ii) * 1024);
  }

  for (int k0 = 0; k0 < 1024; k0 += 64) {
    __syncthreads();
    int cb = (k0 >> 6) & 1, nb = cb ^ 1;
    if (k0 < 960) {
#pragma unroll
      for (int ii = 0; ii < 4; ++ii) {
        gld_lds16(Asrc[ii] + k0 + 64, (char*)&sA[nb][0] + (w * 4 + ii) * 1024);
        gld_lds16(Bsrc[ii] + k0 + 64, (char*)&sB[nb][0] + (w * 4 + ii) * 1024);
      }
    }
    const char* a8 = (const char*)&sA[cb][0] + abase;
    const char* b8 = (const char*)&sB[cb][0] + bbase;
#pragma unroll
    for (int kk = 0; kk < 2; ++kk) {
      const int yk = kk ? y1 : y0;
      bf16x8 af[4], bfr[4];
#pragma unroll
      for (int m = 0; m < 4; ++m)
        af[m] = *(const bf16x8*)(a8 + m * 2048 + yk);
#pragma unroll
      for (int n = 0; n < 4; ++n)
        bfr[n] = *(const bf16x8*)(b8 + n * 2048 + yk);
#pragma unroll
      for (int m = 0; m < 4; ++m)
#pragma unroll
        for (int n = 0; n < 4; ++n)
          acc[m][n] = __builtin_amdgcn_mfma_f32_16x16x32_bf16(af[m], bfr[n], acc[m][n], 0, 0, 0);
    }
  }

  float csc = (EPI == 0 && isK) ? 1.0f : cscale;
#pragma unroll
  for (int m = 0; m < 4; ++m) {
    int row_base = row0 + wr * 64 + m * 16 + g * 4;
#pragma unroll
    for (int n = 0; n < 4; ++n) {
      int col = col0 + wc * 64 + n * 16 + c;
#pragma unroll
      for (int r = 0; r < 4; ++r) {
        int row = row_base + r;
        float val = acc[m][n][r];
        if (EPI == 0) {
          int rl = row & 8191;
          int b = rl >> 11, l = rl & 2047, h = col >> 6, d = col & 63;
          bf16* dst = isK ? (bf16*)Cout2 : (bf16*)Cout;
          dst[(((size_t)(b * 16 + h) * 2048 + l) << 6) + d] = (bf16)(val * csc);
        } else if (EPI == 1) {
          ((bf16*)Cout)[((size_t)(bz * 1024 + row)) * 2048 + col] = (bf16)val;
        } else {
          ((float*)Cout)[(size_t)row * 1024 + col] = val + bias[col];
        }
      }
    }
  }
}

// ---------------- stage 3: flash attention (R3 structure + VALU diet) ----------------
// Single barrier per KV tile, dbuf reg-staged K/V, static-m softmax (Q pre-scaled
// by log2e/8), denominator via mfma(ones, P) on the idle matrix pipe.
__global__ __launch_bounds__(256, 3)
void attn_fwd(const bf16* __restrict__ Qp, const bf16* __restrict__ Kp,
              const bf16* __restrict__ Vt, const u32* __restrict__ mbits,
              bf16* __restrict__ X) {
  int lin = blockIdx.y * 16 + blockIdx.x;
  int swz = (lin & 7) * 128 + (lin >> 3);
  int qt = swz & 15, bh = swz >> 4;
  int b = bh >> 4, h = bh & 15;
  int q0 = qt * 128;

  const int tid = threadIdx.x;
  const int lane = tid & 63, w = tid >> 6;
  const int c = lane & 15, g = lane >> 4;

  __shared__ char smem[49152];
  char* sKV = smem;                        // 2 slots x {K 8K | V 8K}, XOR swizzled
  char* sPw = smem + 32768 + w * 4096;     // per-wave P: [32 q][64 keys] bf16

  const int c7 = c & 7;
  const int y0 = (g ^ c7) << 4;
  const int y1 = ((4 + g) ^ c7) << 4;
  const int ko0 = c * 128 + y0;
  const int ko1 = c * 128 + y1;
  const int vo0 = 8192 + c * 128 + y0;
  const int vo1 = 8192 + c * 128 + y1;
  const char* paddr0 = sPw + c * 128 + y0;
  const char* paddr1 = sPw + c * 128 + y1;
  char* pw[4];
#pragma unroll
  for (int nk = 0; nk < 4; ++nk)
    pw[nk] = sPw + c * 128 + ((g & 1) * 8) + (((nk * 2 + (g >> 1)) ^ c7) << 4);

  const int r0 = tid >> 3, bb0 = tid & 7;
  const int r1 = (256 + tid) >> 3, bb1 = tid & 7;
  const int dK0 = r0 * 128 + ((bb0 ^ (r0 & 7)) << 4);
  const int dK1 = r1 * 128 + ((bb1 ^ (r1 & 7)) << 4);
  const int dV0 = 8192 + dK0;
  const int dV1 = 8192 + dK1;
  const bf16* gK0 = Kp + (size_t)bh * 131072 + r0 * 64 + bb0 * 8;
  const bf16* gK1 = Kp + (size_t)bh * 131072 + r1 * 64 + bb1 * 8;
  const bf16* gV0 = Vt + ((size_t)(b * 1024 + h * 64 + r0)) * 2048 + bb0 * 8;
  const bf16* gV1 = Vt + ((size_t)(b * 1024 + h * 64 + r1)) * 2048 + bb1 * 8;

  const bf16* Qbase = Qp + ((size_t)bh * 2048) * 64;
  bf16x8 qf[2][2];
#pragma unroll
  for (int nq = 0; nq < 2; ++nq) {
    int qg = q0 + w * 32 + nq * 16 + c;
#pragma unroll
    for (int kk = 0; kk < 2; ++kk)
      qf[nq][kk] = *(const bf16x8*)&Qbase[(size_t)qg * 64 + kk * 32 + g * 8];
  }

  bf16x8 onesv;
#pragma unroll
  for (int i = 0; i < 8; ++i) onesv[i] = (bf16)1.0f;

  const u64* Mrow0 = (const u64*)(mbits + ((size_t)b * 2048 + (q0 + w * 32 + c)) * 64);
  const u64* Mrow1 = (const u64*)(mbits + ((size_t)b * 2048 + (q0 + w * 32 + 16 + c)) * 64);

  f32x4 oacc[4][2] = {};                  // [md][nq] : O^T[d][q]
  f32x4 dacc[2] = {};                     // softmax denominators via mfma(ones,P)

  // prologue: tile 0 -> regs -> LDS buf 0
  {
    uint4 kr0 = *(const uint4*)gK0, kr1 = *(const uint4*)gK1;
    uint4 vr0 = *(const uint4*)gV0, vr1 = *(const uint4*)gV1;
    *(uint4*)(sKV + dK0) = kr0; *(uint4*)(sKV + dK1) = kr1;
    *(uint4*)(sKV + dV0) = vr0; *(uint4*)(sKV + dV1) = vr1;
  }
  u64 mw0 = Mrow0[0], mw1 = Mrow1[0];

  for (int t = 0; t < 32; ++t) {
    __syncthreads();                       // buf[t&1] staged & visible; prev reads done
    const char* kbuf = sKV + ((t & 1) << 14);

    uint4 kr0, kr1, vr0, vr1;
    u64 mn0 = 0, mn1 = 0;
    if (t < 31) {
      kr0 = *(const uint4*)(gK0 + (size_t)(t + 1) * 4096);
      kr1 = *(const uint4*)(gK1 + (size_t)(t + 1) * 4096);
      vr0 = *(const uint4*)(gV0 + (size_t)(t + 1) * 64);
      vr1 = *(const uint4*)(gV1 + (size_t)(t + 1) * 64);
      mn0 = Mrow0[t + 1];
      mn1 = Mrow1[t + 1];
    }

    // QK^T (swapped): St[key][q]
    f32x4 st[4][2] = {};
    __builtin_amdgcn_s_setprio(1);
#pragma unroll
    for (int nk = 0; nk < 4; ++nk) {
      bf16x8 kfa = *(const bf16x8*)(kbuf + ko0 + nk * 2048);
      st[nk][0] = __builtin_amdgcn_mfma_f32_16x16x32_bf16(kfa, qf[0][0], st[nk][0], 0, 0, 0);
      st[nk][1] = __builtin_amdgcn_mfma_f32_16x16x32_bf16(kfa, qf[1][0], st[nk][1], 0, 0, 0);
      bf16x8 kfb = *(const bf16x8*)(kbuf + ko1 + nk * 2048);
      st[nk][0] = __builtin_amdgcn_mfma_f32_16x16x32_bf16(kfb, qf[0][1], st[nk][0], 0, 0, 0);
      st[nk][1] = __builtin_amdgcn_mfma_f32_16x16x32_bf16(kfb, qf[1][1], st[nk][1], 0, 0, 0);
    }
    __builtin_amdgcn_s_setprio(0);

    // static-m softmax: p = mask ? exp2(st) : 0 ; pack bf16 quads -> LDS
#pragma unroll
    for (int nq = 0; nq < 2; ++nq) {
      u64 ms = (nq ? mw1 : mw0) >> (4 * g);   // bit (16*nk + r) is key nk*16+g*4+r
      u32 ma = (u32)ms;
      u32 mb2 = (u32)(ms >> 32);
#pragma unroll
      for (int nk = 0; nk < 4; ++nk) {
        u32 msel = (nk < 2) ? ma : mb2;
        const int bs = (nk & 1) * 16;
        float e0 = __builtin_amdgcn_exp2f(st[nk][nq][0]);
        float e1 = __builtin_amdgcn_exp2f(st[nk][nq][1]);
        float e2 = __builtin_amdgcn_exp2f(st[nk][nq][2]);
        float e3 = __builtin_amdgcn_exp2f(st[nk][nq][3]);
        e0 = (msel & (1u << (bs + 0))) ? e0 : 0.f;
        e1 = (msel & (1u << (bs + 1))) ? e1 : 0.f;
        e2 = (msel & (1u << (bs + 2))) ? e2 : 0.f;
        e3 = (msel & (1u << (bs + 3))) ? e3 : 0.f;
        union { bf16 hh[4]; uint2 dd; } pk;
        pk.hh[0] = (bf16)e0; pk.hh[1] = (bf16)e1;
        pk.hh[2] = (bf16)e2; pk.hh[3] = (bf16)e3;
        *(uint2*)(pw[nk] + nq * 2048) = pk.dd;
      }
    }

    // PV: O^T[d][q] += Vt . P^T ; denominator rows via mfma(ones, P)
    __builtin_amdgcn_s_setprio(1);
#pragma unroll
    for (int kk = 0; kk < 2; ++kk) {
      const char* pa = kk ? paddr1 : paddr0;
      const int vo = kk ? vo1 : vo0;
      bf16x8 pf0 = *(const bf16x8*)(pa);
      bf16x8 pf1 = *(const bf16x8*)(pa + 2048);
      dacc[0] = __builtin_amdgcn_mfma_f32_16x16x32_bf16(onesv, pf0, dacc[0], 0, 0, 0);
      dacc[1] = __builtin_amdgcn_mfma_f32_16x16x32_bf16(onesv, pf1, dacc[1], 0, 0, 0);
#pragma unroll
      for (int md = 0; md < 4; ++md) {
        bf16x8 vf = *(const bf16x8*)(kbuf + vo + md * 2048);
        oacc[md][0] = __builtin_amdgcn_mfma_f32_16x16x32_bf16(vf, pf0, oacc[md][0], 0, 0, 0);
        oacc[md][1] = __builtin_amdgcn_mfma_f32_16x16x32_bf16(vf, pf1, oacc[md][1], 0, 0, 0);
      }
    }
    __builtin_amdgcn_s_setprio(0);

    // write next tile into buf^1 (loads have had the whole compute to land)
    if (t < 31) {
      char* nbuf = sKV + (((t + 1) & 1) << 14);
      *(uint4*)(nbuf + dK0) = kr0; *(uint4*)(nbuf + dK1) = kr1;
      *(uint4*)(nbuf + dV0) = vr0; *(uint4*)(nbuf + dV1) = vr1;
    }
    mw0 = mn0; mw1 = mn1;
  }

  float inv0 = 1.f / dacc[0][0];
  float inv1 = 1.f / dacc[1][0];

  // epilogue: O^T -> LDS transpose -> coalesced bf16 write
  __syncthreads();
  char* Xl = smem;
#pragma unroll
  for (int nq = 0; nq < 2; ++nq) {
    float inv = nq ? inv1 : inv0;
    int ql = w * 32 + nq * 16 + c;
#pragma unroll
    for (int md = 0; md < 4; ++md)
#pragma unroll
      for (int r = 0; r < 4; ++r) {
        int d = md * 16 + g * 4 + r;
        int blk = d >> 3, off = d & 7;
        *(bf16*)(Xl + ql * 128 + ((blk ^ (ql & 7)) << 4) + off * 2) =
            (bf16)(oacc[md][nq][r] * inv);
      }
  }
  __syncthreads();
#pragma unroll
  for (int i = 0; i < 4; ++i) {
    int u = i * 256 + tid;
    int row = u >> 3, blk = u & 7;
    uint4 xv = *(const uint4*)(Xl + row * 128 + ((blk ^ (row & 7)) << 4));
    *(uint4*)&X[(size_t)(b * 2048 + q0 + row) * 1024 + h * 64 + blk * 8] = xv;
  }
}

// ---------------- launch ----------------

extern "C" void kernel_launch(void* const* d_in, const int* in_sizes, int n_in,
                              void* d_out, int out_size, void* d_ws, size_t ws_size,
                              hipStream_t stream) {
  const float* q    = (const float*)d_in[0];
  const float* k    = (const float*)d_in[1];
  const float* v    = (const float*)d_in[2];
  const int*   mask = (const int*)d_in[3];
  const float* Wq   = (const float*)d_in[4];
  const float* Wk   = (const float*)d_in[5];
  const float* Wv   = (const float*)d_in[6];
  const float* Wo   = (const float*)d_in[7];
  const float* Wb   = (const float*)d_in[8];

  char* ws = (char*)d_ws;
  bf16* qb = (bf16*)(ws + 0);
  bf16* kb = (bf16*)(ws + 16777216);
  bf16* vb = (bf16*)(ws + 33554432);
  bf16* Wt = (bf16*)(ws + 50331648);
  bf16* Qp = (bf16*)(ws + 58720256);
  bf16* Kp = (bf16*)(ws + 75497472);
  bf16* Vt = (bf16*)(ws + 92274688);
  bf16* Xb = (bf16*)(ws + 109051904);
  u32*  mb = (u32*) (ws + 125829120);

  cvt3<<<dim3(512, 1, 3), 256, 0, stream>>>(q, k, v, qb);
  pack_w<<<dim3(512, 1, 4), 256, 0, stream>>>(Wq, Wk, Wv, Wo, Wt);
  pack_mask<<<2048, 256, 0, stream>>>(mask, mb, 16777216);

  // fused: Q = (q.Wq)*log2e/8 and K = k.Wk  -> [bh][l][d]
  gemm_bt<0><<<dim3(8, 128, 1), 256, 0, stream>>>(qb, Wt, Qp, Kp, nullptr, 0, 0, SCALE_L2E);
  // Vt[b][hd][l] = Wv^T . v^T  per batch
  gemm_bt<1><<<dim3(16, 8, 4), 256, 0, stream>>>(Wt + 2097152, vb, Vt, nullptr, nullptr, 0, 2097152, 1.0f);

  attn_fwd<<<dim3(16, 64, 1), 256, 0, stream>>>(Qp, Kp, Vt, mb, Xb);

  // out = X . Wo^T + b  (f32 out)
  gemm_bt<2><<<dim3(8, 64, 1), 256, 0, stream>>>(Xb, Wt + 3145728, (float*)d_out, nullptr, Wb, 0, 0, 1.0f);
}

// Round 6
// 261.455 us; speedup vs baseline: 1.0435x; 1.0083x over previous
//
#include <hip/hip_runtime.h>
#include <stdint.h>

typedef __bf16 bf16;
typedef __bf16 bf16x8 __attribute__((ext_vector_type(8)));
typedef float  f32x4  __attribute__((ext_vector_type(4)));
typedef uint32_t u32;
typedef uint64_t u64;

#define SCALE_L2E 0.18033688011112042f   // (1/8) * log2(e)

__device__ __forceinline__ void gld_lds16(const void* gsrc, void* ldst) {
  __builtin_amdgcn_global_load_lds(
      (const __attribute__((address_space(1))) void*)gsrc,
      (__attribute__((address_space(3))) void*)ldst, 16, 0, 0);
}

// ---------------- stage 1: fused prep (cvt q/k/v, pack W, pack mask) ----------------
__global__ void prep(const float* __restrict__ q, const float* __restrict__ k,
                     const float* __restrict__ v, const int* __restrict__ mask,
                     const float* __restrict__ Wq, const float* __restrict__ Wk,
                     const float* __restrict__ Wv, const float* __restrict__ Wo,
                     bf16* __restrict__ qkv, bf16* __restrict__ Wt, u32* __restrict__ mbits) {
  const int z = blockIdx.z;
  const int tg = blockIdx.x * 256 + threadIdx.x;        // 0..524287
  if (z < 3) {
    const float* in = (z == 0) ? q : (z == 1) ? k : v;
    bf16* o = qkv + (size_t)z * 8388608;
#pragma unroll
    for (int it = 0; it < 2; ++it) {
      int i = tg + it * 524288;
      const float4* p = (const float4*)(in + (size_t)i * 8);
      float4 a = p[0], b = p[1];
      bf16x8 vv;
      vv[0]=(bf16)a.x; vv[1]=(bf16)a.y; vv[2]=(bf16)a.z; vv[3]=(bf16)a.w;
      vv[4]=(bf16)b.x; vv[5]=(bf16)b.y; vv[6]=(bf16)b.z; vv[7]=(bf16)b.w;
      *(bf16x8*)(o + (size_t)i * 8) = vv;
    }
  } else if (z == 3) {
    int s = tg >> 17;                                    // 0..3
    int t = tg & 131071;
    int n = t >> 7, kb = t & 127;
    const float* W = (s == 0) ? Wq : (s == 1) ? Wk : (s == 2) ? Wv : Wo;
    bf16x8 vv;
    if (s < 3) {
#pragma unroll
      for (int j = 0; j < 8; ++j)
        vv[j] = (bf16)W[((n >> 6) << 16) + (kb * 8 + j) * 64 + (n & 63)];
    } else {
      const float4* p = (const float4*)&W[n * 1024 + kb * 8];
      float4 a = p[0], b = p[1];
      vv[0]=(bf16)a.x; vv[1]=(bf16)a.y; vv[2]=(bf16)a.z; vv[3]=(bf16)a.w;
      vv[4]=(bf16)b.x; vv[5]=(bf16)b.y; vv[6]=(bf16)b.z; vv[7]=(bf16)b.w;
    }
    *(bf16x8*)&Wt[(size_t)s * 1048576 + (size_t)n * 1024 + kb * 8] = vv;
  } else {
    for (int idx = tg; idx < 16777216; idx += 524288) {
      int m = mask[idx];
      u64 bal = __ballot(m != 0);
      if ((threadIdx.x & 63) == 0)
        *(u64*)&mbits[idx >> 5] = bal;
    }
  }
}

// ---------------- GEMM core (BK=64, XOR-swizzled LDS, dbuf) shared by both GEMM kernels ----

#define GEMM_CORE(Ap_, Bp_)                                                    \
  __shared__ bf16 sA[2][8192];                                                 \
  __shared__ bf16 sB[2][8192];                                                 \
  const int lane = threadIdx.x & 63, w = threadIdx.x >> 6;                     \
  const int c = lane & 15, g = lane >> 4;                                      \
  const int wr = w >> 1, wc = w & 1;                                           \
  const int c7 = c & 7;                                                        \
  const int ric = lane >> 3;                                                   \
  const int pblk = (lane & 7) ^ (ric & 7);                                     \
  const bf16* Asrc[4];                                                         \
  const bf16* Bsrc[4];                                                         \
  _Pragma("unroll")                                                            \
  for (int ii = 0; ii < 4; ++ii) {                                             \
    int r = 8 * (w * 4 + ii) + ric;                                            \
    Asrc[ii] = (Ap_) + (size_t)r * 1024 + pblk * 8;                            \
    Bsrc[ii] = (Bp_) + (size_t)r * 1024 + pblk * 8;                            \
  }                                                                            \
  const int y0 = (g ^ c7) << 4;                                                \
  const int y1 = ((4 + g) ^ c7) << 4;                                          \
  const int abase = wr * 8192 + c * 128;                                       \
  const int bbase = wc * 8192 + c * 128;                                       \
  f32x4 acc[4][4] = {};                                                        \
  _Pragma("unroll")                                                            \
  for (int ii = 0; ii < 4; ++ii) {                                             \
    gld_lds16(Asrc[ii], (char*)&sA[0][0] + (w * 4 + ii) * 1024);               \
    gld_lds16(Bsrc[ii], (char*)&sB[0][0] + (w * 4 + ii) * 1024);               \
  }                                                                            \
  for (int k0 = 0; k0 < 1024; k0 += 64) {                                      \
    __syncthreads();                                                           \
    int cb = (k0 >> 6) & 1, nb = cb ^ 1;                                       \
    if (k0 < 960) {                                                            \
      _Pragma("unroll")                                                        \
      for (int ii = 0; ii < 4; ++ii) {                                         \
        gld_lds16(Asrc[ii] + k0 + 64, (char*)&sA[nb][0] + (w * 4 + ii) * 1024);\
        gld_lds16(Bsrc[ii] + k0 + 64, (char*)&sB[nb][0] + (w * 4 + ii) * 1024);\
      }                                                                        \
    }                                                                          \
    const char* a8 = (const char*)&sA[cb][0] + abase;                          \
    const char* b8 = (const char*)&sB[cb][0] + bbase;                          \
    _Pragma("unroll")                                                          \
    for (int kk = 0; kk < 2; ++kk) {                                           \
      const int yk = kk ? y1 : y0;                                             \
      bf16x8 af[4], bfr[4];                                                    \
      _Pragma("unroll")                                                        \
      for (int m = 0; m < 4; ++m)                                              \
        af[m] = *(const bf16x8*)(a8 + m * 2048 + yk);                          \
      _Pragma("unroll")                                                        \
      for (int n = 0; n < 4; ++n)                                              \
        bfr[n] = *(const bf16x8*)(b8 + n * 2048 + yk);                         \
      _Pragma("unroll")                                                        \
      for (int m = 0; m < 4; ++m)                                              \
        _Pragma("unroll")                                                      \
        for (int n = 0; n < 4; ++n)                                            \
          acc[m][n] = __builtin_amdgcn_mfma_f32_16x16x32_bf16(af[m], bfr[n], acc[m][n], 0, 0, 0); \
    }                                                                          \
  }

// fused projections: wgs 0..1023 -> Q|K (M=16384 over qb|kb), wgs 1024..1535 -> Vt
__global__ __launch_bounds__(256, 2)
void proj_fused(const bf16* __restrict__ qkv, const bf16* __restrict__ Wt,
                bf16* __restrict__ Qp, bf16* __restrict__ Kp, bf16* __restrict__ Vt) {
  const int wg = blockIdx.x;
  const bf16* Ap;
  const bf16* Bp;
  int row0, col0, stage;
  if (wg < 1024) {
    int swz = (wg & 7) * 128 + (wg >> 3);
    int bx = swz & 7, by = swz >> 3;
    row0 = by * 128; col0 = bx * 128;
    stage = (row0 >= 8192) ? 1 : 0;                  // 0=Q, 1=K
    Ap = qkv + (size_t)row0 * 1024;                  // qb|kb contiguous
    Bp = Wt + (stage ? 1048576 : 0) + (size_t)col0 * 1024;
  } else {
    int w2 = wg - 1024;
    int bz = w2 >> 7, rem = w2 & 127;
    int swz = (rem & 7) * 16 + (rem >> 3);
    int bx = swz & 15, by = swz >> 4;
    row0 = by * 128; col0 = bx * 128;
    stage = 2 + bz;                                   // Vt, batch bz
    Ap = Wt + 2097152 + (size_t)row0 * 1024;
    Bp = qkv + 16777216 + (size_t)bz * 2097152 + (size_t)col0 * 1024;  // vb
  }

  GEMM_CORE(Ap, Bp)

  if (stage <= 1) {
    float csc = stage ? 1.0f : SCALE_L2E;
    bf16* dst = stage ? Kp : Qp;
#pragma unroll
    for (int m = 0; m < 4; ++m) {
      int row_base = (row0 & 8191) + wr * 64 + m * 16 + g * 4;
#pragma unroll
      for (int n = 0; n < 4; ++n) {
        int col = col0 + wc * 64 + n * 16 + c;
#pragma unroll
        for (int r = 0; r < 4; ++r) {
          int row = row_base + r;
          int b = row >> 11, l = row & 2047, h = col >> 6, d = col & 63;
          dst[(((size_t)(b * 16 + h) * 2048 + l) << 6) + d] = (bf16)(acc[m][n][r] * csc);
        }
      }
    }
  } else {
    int bz = stage - 2;
#pragma unroll
    for (int m = 0; m < 4; ++m) {
      int row_base = row0 + wr * 64 + m * 16 + g * 4;
#pragma unroll
      for (int n = 0; n < 4; ++n) {
        int col = col0 + wc * 64 + n * 16 + c;
#pragma unroll
        for (int r = 0; r < 4; ++r)
          Vt[((size_t)(bz * 1024 + row_base + r)) * 2048 + col] = (bf16)acc[m][n][r];
      }
    }
  }
}

// output projection: out = X . Wo^T + b (f32)
__global__ __launch_bounds__(256, 2)
void gemm_out(const bf16* __restrict__ X, const bf16* __restrict__ Wot,
              float* __restrict__ out, const float* __restrict__ bias) {
  int lin = blockIdx.y * 8 + blockIdx.x;
  int swz = (lin & 7) * 64 + (lin >> 3);
  int bx = swz & 7, by = swz >> 3;
  const int row0 = by * 128, col0 = bx * 128;
  const bf16* Ap = X + (size_t)row0 * 1024;
  const bf16* Bp = Wot + (size_t)col0 * 1024;

  GEMM_CORE(Ap, Bp)

#pragma unroll
  for (int m = 0; m < 4; ++m) {
    int row_base = row0 + wr * 64 + m * 16 + g * 4;
#pragma unroll
    for (int n = 0; n < 4; ++n) {
      int col = col0 + wc * 64 + n * 16 + c;
#pragma unroll
      for (int r = 0; r < 4; ++r)
        out[(size_t)(row_base + r) * 1024 + col] = acc[m][n][r] + bias[col];
    }
  }
}

// ---------------- stage 3: flash attention, KVBLK=32, 24KB LDS, 4 blocks/CU ----------------
// Swapped QK^T (St[key][q]); static-m softmax (Q pre-scaled by log2e/8);
// denominator via mfma(ones,P); dbuf KV; paired-row XOR-swizzled V/P layouts.
__global__ __launch_bounds__(256, 4)
void attn_fwd(const bf16* __restrict__ Qp, const bf16* __restrict__ Kp,
              const bf16* __restrict__ Vt, const u32* __restrict__ mbits,
              bf16* __restrict__ X) {
  int lin = blockIdx.y * 16 + blockIdx.x;
  int swz = (lin & 7) * 128 + (lin >> 3);
  int qt = swz & 15, bh = swz >> 4;
  int b = bh >> 4, h = bh & 15;
  int q0 = qt * 128;

  const int tid = threadIdx.x;
  const int lane = tid & 63, w = tid >> 6;
  const int c = lane & 15, g = lane >> 4;

  __shared__ char smem[24576];
  char* sKV = smem;                        // 2 slots x {K 4KB | V 4KB}
  char* sPw = smem + 16384 + w * 2048;     // per-wave P: [32 q][32 keys] bf16, paired rows

  const int c7 = c & 7;
  // K fragment reads: row=key (128B rows, 8 blocks), block kk*4+g, XOR (c&7)
  const int ko0 = c * 128 + ((g ^ c7) << 4);
  const int ko1 = c * 128 + (((4 + g) ^ c7) << 4);
  // V / P fragment reads: paired rows rr=(row>>1), blk' = (row&1)*4+g, XOR (rr&7)=(c>>1)
  const int pr_off = (c >> 1) * 128 + ((((c & 1) * 4 + g) ^ (c >> 1)) << 4);
  // P writes: key0 = nk*16+g*4 -> block nk*2+(g>>1), byte (g&1)*8
  int pwo[2];
#pragma unroll
  for (int nk = 0; nk < 2; ++nk)
    pwo[nk] = (c >> 1) * 128 + ((((c & 1) * 4 + nk * 2 + (g >> 1)) ^ (c >> 1)) << 4) + (g & 1) * 8;

  // staging (per thread, one uint4 each for K and V)
  const int kr_ = tid >> 3, kb_ = tid & 7;
  const int dK = kr_ * 128 + ((kb_ ^ (kr_ & 7)) << 4);
  const int vd_ = tid >> 2, vk_ = tid & 3;
  const int dV = 4096 + (vd_ >> 1) * 128 + (((((vd_ & 1) << 2) + vk_) ^ ((vd_ >> 1) & 7)) << 4);
  const bf16* gK = Kp + (size_t)bh * 131072 + kr_ * 64 + kb_ * 8;
  const bf16* gV = Vt + ((size_t)(b * 1024 + h * 64 + vd_)) * 2048 + vk_ * 8;

  const bf16* Qbase = Qp + ((size_t)bh * 2048) * 64;
  bf16x8 qf[2][2];
#pragma unroll
  for (int nq = 0; nq < 2; ++nq) {
    int qg = q0 + w * 32 + nq * 16 + c;
#pragma unroll
    for (int kk = 0; kk < 2; ++kk)
      qf[nq][kk] = *(const bf16x8*)&Qbase[(size_t)qg * 64 + kk * 32 + g * 8];
  }

  bf16x8 onesv;
#pragma unroll
  for (int i = 0; i < 8; ++i) onesv[i] = (bf16)1.0f;

  const u32* Mrow0 = mbits + ((size_t)b * 2048 + (q0 + w * 32 + c)) * 64;
  const u32* Mrow1 = mbits + ((size_t)b * 2048 + (q0 + w * 32 + 16 + c)) * 64;

  f32x4 oacc[4][2] = {};                  // [md][nq] : O^T[d][q]
  f32x4 dacc[2] = {};

  // prologue: tile 0 -> regs -> LDS slot 0
  {
    uint4 kr = *(const uint4*)gK;
    uint4 vr = *(const uint4*)gV;
    *(uint4*)(sKV + dK) = kr;
    *(uint4*)(sKV + dV) = vr;
  }
  u32 mw0 = Mrow0[0], mw1 = Mrow1[0];

  for (int t = 0; t < 64; ++t) {
    __syncthreads();
    const char* kbuf = sKV + ((t & 1) << 13);

    uint4 kr, vr;
    u32 mn0 = 0, mn1 = 0;
    if (t < 63) {
      kr = *(const uint4*)(gK + (size_t)(t + 1) * 2048);
      vr = *(const uint4*)(gV + (size_t)(t + 1) * 32);
      mn0 = Mrow0[t + 1];
      mn1 = Mrow1[t + 1];
    }

    // QK^T (swapped): St[key][q], 32 keys
    f32x4 st[2][2] = {};
    __builtin_amdgcn_s_setprio(1);
#pragma unroll
    for (int nk = 0; nk < 2; ++nk) {
      bf16x8 kfa = *(const bf16x8*)(kbuf + ko0 + nk * 2048);
      st[nk][0] = __builtin_amdgcn_mfma_f32_16x16x32_bf16(kfa, qf[0][0], st[nk][0], 0, 0, 0);
      st[nk][1] = __builtin_amdgcn_mfma_f32_16x16x32_bf16(kfa, qf[1][0], st[nk][1], 0, 0, 0);
      bf16x8 kfb = *(const bf16x8*)(kbuf + ko1 + nk * 2048);
      st[nk][0] = __builtin_amdgcn_mfma_f32_16x16x32_bf16(kfb, qf[0][1], st[nk][0], 0, 0, 0);
      st[nk][1] = __builtin_amdgcn_mfma_f32_16x16x32_bf16(kfb, qf[1][1], st[nk][1], 0, 0, 0);
    }
    __builtin_amdgcn_s_setprio(0);

    // static-m softmax: p = mask ? exp2(st) : 0 ; pack bf16 quads -> LDS
#pragma unroll
    for (int nq = 0; nq < 2; ++nq) {
      u32 ms = (nq ? mw1 : mw0) >> (4 * g);   // bit (16*nk + r) is key nk*16+g*4+r
#pragma unroll
      for (int nk = 0; nk < 2; ++nk) {
        const int bs = nk * 16;
        float e0 = __builtin_amdgcn_exp2f(st[nk][nq][0]);
        float e1 = __builtin_amdgcn_exp2f(st[nk][nq][1]);
        float e2 = __builtin_amdgcn_exp2f(st[nk][nq][2]);
        float e3 = __builtin_amdgcn_exp2f(st[nk][nq][3]);
        e0 = (ms & (1u << (bs + 0))) ? e0 : 0.f;
        e1 = (ms & (1u << (bs + 1))) ? e1 : 0.f;
        e2 = (ms & (1u << (bs + 2))) ? e2 : 0.f;
        e3 = (ms & (1u << (bs + 3))) ? e3 : 0.f;
        union { bf16 hh[4]; uint2 dd; } pk;
        pk.hh[0] = (bf16)e0; pk.hh[1] = (bf16)e1;
        pk.hh[2] = (bf16)e2; pk.hh[3] = (bf16)e3;
        *(uint2*)(sPw + pwo[nk] + nq * 1024) = pk.dd;
      }
    }

    // PV: O^T[d][q] += Vt . P^T (single k=32 step); denominator via mfma(ones,P)
    __builtin_amdgcn_s_setprio(1);
    {
      bf16x8 pf0 = *(const bf16x8*)(sPw + pr_off);
      bf16x8 pf1 = *(const bf16x8*)(sPw + pr_off + 1024);
      dacc[0] = __builtin_amdgcn_mfma_f32_16x16x32_bf16(onesv, pf0, dacc[0], 0, 0, 0);
      dacc[1] = __builtin_amdgcn_mfma_f32_16x16x32_bf16(onesv, pf1, dacc[1], 0, 0, 0);
#pragma unroll
      for (int md = 0; md < 4; ++md) {
        bf16x8 vf = *(const bf16x8*)(kbuf + 4096 + pr_off + md * 1024);
        oacc[md][0] = __builtin_amdgcn_mfma_f32_16x16x32_bf16(vf, pf0, oacc[md][0], 0, 0, 0);
        oacc[md][1] = __builtin_amdgcn_mfma_f32_16x16x32_bf16(vf, pf1, oacc[md][1], 0, 0, 0);
      }
    }
    __builtin_amdgcn_s_setprio(0);

    if (t < 63) {
      char* nbuf = sKV + (((t + 1) & 1) << 13);
      *(uint4*)(nbuf + dK) = kr;
      *(uint4*)(nbuf + dV) = vr;
    }
    mw0 = mn0; mw1 = mn1;
  }

  float inv0 = 1.f / dacc[0][0];
  float inv1 = 1.f / dacc[1][0];

  // epilogue: O^T -> LDS transpose -> coalesced bf16 write
  __syncthreads();
  char* Xl = smem;                         // 16KB: [128 q][64 d] bf16, swizzled
#pragma unroll
  for (int nq = 0; nq < 2; ++nq) {
    float inv = nq ? inv1 : inv0;
    int ql = w * 32 + nq * 16 + c;
#pragma unroll
    for (int md = 0; md < 4; ++md)
#pragma unroll
      for (int r = 0; r < 4; ++r) {
        int d = md * 16 + g * 4 + r;
        int blk = d >> 3, off = d & 7;
        *(bf16*)(Xl + ql * 128 + ((blk ^ (ql & 7)) << 4) + off * 2) =
            (bf16)(oacc[md][nq][r] * inv);
      }
  }
  __syncthreads();
#pragma unroll
  for (int i = 0; i < 4; ++i) {
    int u = i * 256 + tid;
    int row = u >> 3, blk = u & 7;
    uint4 xv = *(const uint4*)(Xl + row * 128 + ((blk ^ (row & 7)) << 4));
    *(uint4*)&X[(size_t)(b * 2048 + q0 + row) * 1024 + h * 64 + blk * 8] = xv;
  }
}

// ---------------- launch ----------------

extern "C" void kernel_launch(void* const* d_in, const int* in_sizes, int n_in,
                              void* d_out, int out_size, void* d_ws, size_t ws_size,
                              hipStream_t stream) {
  const float* q    = (const float*)d_in[0];
  const float* k    = (const float*)d_in[1];
  const float* v    = (const float*)d_in[2];
  const int*   mask = (const int*)d_in[3];
  const float* Wq   = (const float*)d_in[4];
  const float* Wk   = (const float*)d_in[5];
  const float* Wv   = (const float*)d_in[6];
  const float* Wo   = (const float*)d_in[7];
  const float* Wb   = (const float*)d_in[8];

  char* ws = (char*)d_ws;
  bf16* qkv = (bf16*)(ws + 0);             // qb|kb|vb contiguous, 48 MB
  bf16* Wt  = (bf16*)(ws + 50331648);      // 8 MB (4 packed 1024x1024)
  bf16* Qp  = (bf16*)(ws + 58720256);
  bf16* Kp  = (bf16*)(ws + 75497472);
  bf16* Vt  = (bf16*)(ws + 92274688);
  bf16* Xb  = (bf16*)(ws + 109051904);
  u32*  mb  = (u32*) (ws + 125829120);     // 2 MB bitmask

  prep<<<dim3(2048, 1, 5), 256, 0, stream>>>(q, k, v, mask, Wq, Wk, Wv, Wo, qkv, Wt, mb);

  proj_fused<<<dim3(1536, 1, 1), 256, 0, stream>>>(qkv, Wt, Qp, Kp, Vt);

  attn_fwd<<<dim3(16, 64, 1), 256, 0, stream>>>(Qp, Kp, Vt, mb, Xb);

  gemm_out<<<dim3(8, 64, 1), 256, 0, stream>>>(Xb, Wt + 3145728, (float*)d_out, Wb);
}